// Round 5
// baseline (2024.209 us; speedup 1.0000x reference)
//
#include <hip/hip_runtime.h>

#define HID   2048
#define INTER 8192
#define NEXP  8
#define NTOK  16384   // 4 * 4096

typedef unsigned short u16;
typedef __bf16 bf16x8 __attribute__((ext_vector_type(8)));
typedef float  floatx4 __attribute__((ext_vector_type(4)));
typedef u16    u16x4   __attribute__((ext_vector_type(4)));

typedef __attribute__((address_space(3))) void       lds_void_t;
typedef const __attribute__((address_space(1))) void gbl_void_t;

__device__ __forceinline__ u16 f2bf(float f) {
    union { float f; unsigned u; } v; v.f = f;
    unsigned r = v.u + 0x7fffu + ((v.u >> 16) & 1u);  // round-to-nearest-even
    return (u16)(r >> 16);
}

__device__ __forceinline__ void load_lds16(const void* g, void* l) {
    __builtin_amdgcn_global_load_lds((gbl_void_t*)g, (lds_void_t*)l, 16, 0, 0);
}

#define VM_WAIT(n)   asm volatile("s_waitcnt vmcnt(" #n ")" ::: "memory")
#define LGKM_WAIT0() asm volatile("s_waitcnt lgkmcnt(0)" ::: "memory")
#define SCHED_FENCE() __builtin_amdgcn_sched_barrier(0)
#define BAR_F() { __builtin_amdgcn_s_barrier(); SCHED_FENCE(); }

// ---------------------------------------------------------------------------
// Kernel 1: per-token gate logits (fp32) -> top-2 sum scale; write x_bf16 and
// xs_bf16 = x * scale. One wave per token, 4 tokens per block.
// ---------------------------------------------------------------------------
__global__ __launch_bounds__(256) void prep_tokens(
    const float* __restrict__ x, const float* __restrict__ gate,
    u16* __restrict__ xb, u16* __restrict__ xsb)
{
    int token = blockIdx.x * 4 + (threadIdx.x >> 6);
    int lane  = threadIdx.x & 63;
    const float* xr = x + (size_t)token * HID;

    float acc[NEXP];
#pragma unroll
    for (int e = 0; e < NEXP; ++e) acc[e] = 0.f;
#pragma unroll
    for (int c = 0; c < 8; ++c) {
        int kbase = lane * 32 + c * 4;
        float4 v = *(const float4*)(xr + kbase);
        float vv[4] = {v.x, v.y, v.z, v.w};
#pragma unroll
        for (int q = 0; q < 4; ++q) {
            const float* g = gate + (size_t)(kbase + q) * NEXP;
            float4 g0 = *(const float4*)(g);
            float4 g1 = *(const float4*)(g + 4);
            acc[0] += vv[q] * g0.x; acc[1] += vv[q] * g0.y;
            acc[2] += vv[q] * g0.z; acc[3] += vv[q] * g0.w;
            acc[4] += vv[q] * g1.x; acc[5] += vv[q] * g1.y;
            acc[6] += vv[q] * g1.z; acc[7] += vv[q] * g1.w;
        }
    }
#pragma unroll
    for (int off = 32; off >= 1; off >>= 1) {
#pragma unroll
        for (int e = 0; e < NEXP; ++e) acc[e] += __shfl_xor(acc[e], off, 64);
    }
    float m1 = acc[0], m2 = -3.4e38f;
#pragma unroll
    for (int e = 1; e < NEXP; ++e) {
        float v = acc[e];
        if (v > m1) { m2 = m1; m1 = v; } else if (v > m2) { m2 = v; }
    }
    float scale = m1 + m2;

    u16* xo  = xb  + (size_t)token * HID;
    u16* xso = xsb + (size_t)token * HID;
#pragma unroll
    for (int c = 0; c < 8; ++c) {
        int idx = (c * 64 + lane) * 4;
        float4 v = *(const float4*)(xr + idx);
        u16x4 b  = { f2bf(v.x), f2bf(v.y), f2bf(v.z), f2bf(v.w) };
        u16x4 bs = { f2bf(v.x * scale), f2bf(v.y * scale),
                     f2bf(v.z * scale), f2bf(v.w * scale) };
        *(u16x4*)(xo  + idx) = b;
        *(u16x4*)(xso + idx) = bs;
    }
}

// ---------------------------------------------------------------------------
// Kernel 2: transpose + cast  in[K][N] fp32 -> out[N][K] bf16
// ---------------------------------------------------------------------------
__global__ __launch_bounds__(256) void transpose_cast(
    const float* __restrict__ in, u16* __restrict__ out, int K, int N)
{
    __shared__ float t[32][33];
    int tx = threadIdx.x & 31;
    int ty = threadIdx.x >> 5;     // 0..7
    int k0 = blockIdx.y * 32, n0 = blockIdx.x * 32;
#pragma unroll
    for (int r = 0; r < 4; ++r)
        t[ty + r * 8][tx] = in[(size_t)(k0 + ty + r * 8) * N + n0 + tx];
    __syncthreads();
#pragma unroll
    for (int r = 0; r < 4; ++r)
        out[(size_t)(n0 + ty + r * 8) * K + k0 + tx] = f2bf(t[tx][ty + r * 8]);
}

// ---------------------------------------------------------------------------
// GEMM core v5: m201-style 8-phase interleave.
// 256x256 tile, BK=64, 512 threads (8 waves 2Mx4N, wave tile 128x64).
// LDS: 2 dbufs x (A 32KB + B 32KB) = 128 KiB.
// Per K-tile = 4 phases, each:
//   { ds_read 4-8 frags  ||  issue 2 global_load_lds (next tile) }
//   barrier; lgkmcnt(0); setprio(1); 16 MFMA (one quadrant); setprio(0); barrier
// Quadrants: (m-half IB, k-half KS) = (0,0),(4,0),(0,1),(4,1); B-frags reload
// per KS, reused across the IB pair.
// Counted vmcnt, never drained mid-loop: staging is split by k-half (cg0 in
// phases 0-1, cg1 in phases 2-3), consumption staggered identically, so
// VM_WAIT(4) before the closing barrier of phases 1 and 3 guarantees exactly
// the k-half read next while 4 loads stay in flight across every barrier.
//
// LDS layout (st_16x32): each operand tile = [rg 0..15][cg 0..1] subtiles of
// [16 rows][32 cols] bf16 = 1024 B, stored contiguously. Within a subtile,
// 16-B granule slot = chunk ^ (2*((r16>>3)&1))  (byte ^= ((byte>>9)&1)<<5).
// One global_load_lds instruction (64 lanes x 16 B) fills exactly one
// subtile linearly; the swizzle is pre-applied to the per-lane GLOBAL source
// chunk (rule #21), LDS dest stays linear. Fragment ds_read_b128 banks:
// 8 lanes per 16-B granule = exact 8-cycle service, conflict-free.
//
// Sync invariants: buffer b^1 (DMA target during tile t) was last read in
// tile t-1, drained by its phase-3 lgkmcnt(0) before its final barrier;
// issues happen after that barrier. k-half guarantees via VM_WAIT(4)+barrier
// transitivity (all waves waited => all subtiles landed).
// ---------------------------------------------------------------------------
#define GM  256
#define GN  256
#define BKt 64
#define TEL (256 * BKt)   // 16384 u16 per operand tile

__device__ __forceinline__ void rd_a4(const u16* Asb, int rgb, int ks, int so,
                                      bf16x8 afq[4])
{
#pragma unroll
    for (int i = 0; i < 4; ++i)
        afq[i] = *(const bf16x8*)(&Asb[((rgb + i) * 2 + ks) * 512 + so]);
}

__device__ __forceinline__ void rd_b4(const u16* Bsb, int rgb, int ks, int so,
                                      bf16x8 bfq[4])
{
#pragma unroll
    for (int j = 0; j < 4; ++j)
        bfq[j] = *(const bf16x8*)(&Bsb[((rgb + j) * 2 + ks) * 512 + so]);
}

template <int IB>
__device__ __forceinline__ void mfma_quad(const bf16x8 afq[4],
                                          const bf16x8 bfq[4],
                                          floatx4 acc[8][4])
{
#pragma unroll
    for (int i = 0; i < 4; ++i)
#pragma unroll
        for (int j = 0; j < 4; ++j)
            acc[IB + i][j] = __builtin_amdgcn_mfma_f32_16x16x32_bf16(
                afq[i], bfq[j], acc[IB + i][j], 0, 0, 0);
}

// One K-tile = 4 phases. I0..I3: per-phase DMA issue statements (2 loads).
// W1/W3: vm-wait statements before the closing barriers of phases 1 and 3.
#define GTILE(t_, I0, I1, I2, I3, W1, W3)                                     \
    {                                                                         \
        const u16* Asb_ = &As[(t_) & 1][0];                                   \
        const u16* Bsb_ = &Bs[(t_) & 1][0];                                   \
        /* phase 0: quadrant (IB=0, ks=0) */                                  \
        rd_a4(Asb_, wm8, 0, so, afq); rd_b4(Bsb_, wn4, 0, so, bfq);           \
        I0 BAR_F();                                                           \
        LGKM_WAIT0(); SCHED_FENCE();                                          \
        __builtin_amdgcn_s_setprio(1); mfma_quad<0>(afq, bfq, acc);           \
        __builtin_amdgcn_s_setprio(0); SCHED_FENCE(); BAR_F();                \
        /* phase 1: quadrant (IB=4, ks=0), bfq reused */                      \
        rd_a4(Asb_, wm8 + 4, 0, so, afq);                                     \
        I1 BAR_F();                                                           \
        LGKM_WAIT0(); SCHED_FENCE();                                          \
        __builtin_amdgcn_s_setprio(1); mfma_quad<4>(afq, bfq, acc);           \
        __builtin_amdgcn_s_setprio(0); SCHED_FENCE(); W1 BAR_F();             \
        /* phase 2: quadrant (IB=0, ks=1) */                                  \
        rd_a4(Asb_, wm8, 1, so, afq); rd_b4(Bsb_, wn4, 1, so, bfq);           \
        I2 BAR_F();                                                           \
        LGKM_WAIT0(); SCHED_FENCE();                                          \
        __builtin_amdgcn_s_setprio(1); mfma_quad<0>(afq, bfq, acc);           \
        __builtin_amdgcn_s_setprio(0); SCHED_FENCE(); BAR_F();                \
        /* phase 3: quadrant (IB=4, ks=1), bfq reused */                      \
        rd_a4(Asb_, wm8 + 4, 1, so, afq);                                     \
        I3 BAR_F();                                                           \
        LGKM_WAIT0(); SCHED_FENCE();                                          \
        __builtin_amdgcn_s_setprio(1); mfma_quad<4>(afq, bfq, acc);           \
        __builtin_amdgcn_s_setprio(0); SCHED_FENCE(); W3 BAR_F();             \
    }

// GEMM1: h = bf16(relu(x @ up)^2), h[NTOK][INTER]. Both operands have
// K-stride HID (A = x_bf16 [NTOK][HID], B = up^T [INTER][HID]).
__global__ __launch_bounds__(512, 2) void gemm_up(
    const u16* __restrict__ A,   // x_bf16 [NTOK][HID]
    const u16* __restrict__ Bt,  // up^T   [INTER][HID]
    u16* __restrict__ H)         // out    [NTOK][INTER]
{
    __shared__ u16 As[2][TEL];
    __shared__ u16 Bs[2][TEL];

    int tid = threadIdx.x;
    int w = tid >> 6, lane = tid & 63;
    int wm = w >> 2, wn = w & 3;
    int quad = lane >> 4, l16 = lane & 15;
    int wm8 = wm * 8, wn4 = wn * 4;

    // XCD chunk swizzle: nwg = 32*64 = 2048, 2048 % 8 == 0 -> simple form.
    int lid = blockIdx.y * 32 + blockIdx.x;
    int swz = (lid & 7) * (2048 / 8) + (lid >> 3);
    int bx = swz & 31, by = swz >> 5;
    int m0 = by * GM, n0 = bx * GN;

    // DMA: wave w stages subtile row-groups {2w, 2w+1} of A and of B.
    // Per-lane source: row = rg*16 + (lane>>2), global chunk pre-swizzled:
    int qp = (lane & 3) ^ (2 * ((lane >> 5) & 1));
    int offA[2];
    offA[0] = (2 * w * 16 + (lane >> 2)) * HID + qp * 8;
    offA[1] = offA[0] + 16 * HID;
    const u16* Ab = A  + (size_t)m0 * HID;
    const u16* Bb = Bt + (size_t)n0 * HID;

    // Fragment read per-lane offset within a subtile (elems):
    int so = l16 * 32 + ((quad ^ (2 * ((l16 >> 3) & 1))) * 8);

    floatx4 acc[8][4];
#pragma unroll
    for (int i = 0; i < 8; ++i)
#pragma unroll
        for (int j = 0; j < 4; ++j) acc[i][j] = (floatx4){0.f, 0.f, 0.f, 0.f};

#define ISSA(it_, s_, cg_)                                                    \
    load_lds16(Ab + (size_t)(offA[s_] + (cg_) * 32 + (it_) * BKt),            \
               &As[(it_) & 1][((2 * w + (s_)) * 2 + (cg_)) * 512])
#define ISSB(it_, s_, cg_)                                                    \
    load_lds16(Bb + (size_t)(offA[s_] + (cg_) * 32 + (it_) * BKt),            \
               &Bs[(it_) & 1][((2 * w + (s_)) * 2 + (cg_)) * 512])

    const int NT = HID / BKt;  // 32
    bf16x8 afq[4], bfq[4];

    // prologue: tile 0, cg0 first then cg1 (same per-wave order as steady)
    ISSA(0, 0, 0); ISSA(0, 1, 0); ISSB(0, 0, 0); ISSB(0, 1, 0);
    ISSA(0, 0, 1); ISSA(0, 1, 1); ISSB(0, 0, 1); ISSB(0, 1, 1);
    VM_WAIT(4);          // cg0 landed (own wave)
    BAR_F();             // ... and everyone else's

    for (int t = 0; t < NT - 1; ++t) {
        GTILE(t,
              { ISSA(t + 1, 0, 0); ISSA(t + 1, 1, 0); },
              { ISSB(t + 1, 0, 0); ISSB(t + 1, 1, 0); },
              { ISSA(t + 1, 0, 1); ISSA(t + 1, 1, 1); },
              { ISSB(t + 1, 0, 1); ISSB(t + 1, 1, 1); },
              VM_WAIT(4);, VM_WAIT(4);)
    }
    GTILE(NT - 1, ;, ;, ;, ;, VM_WAIT(0);, ;)
#undef ISSA
#undef ISSB

    int mrow = m0 + wm * 128;
    int ncol = n0 + wn * 64;
#pragma unroll
    for (int i = 0; i < 8; ++i) {
#pragma unroll
        for (int j = 0; j < 4; ++j) {
            int mbase = mrow + i * 16 + quad * 4;
            int n = ncol + j * 16 + l16;
#pragma unroll
            for (int r = 0; r < 4; ++r) {
                float v = acc[i][j][r];
                v = fmaxf(v, 0.f);
                v = v * v;
                H[(size_t)(mbase + r) * INTER + n] = f2bf(v);
            }
        }
    }
}

// GEMM2: y = h @ down^T (K=8192) + xs @ expert^T (K=2048), fp32 out.
// Phase 1 operands have K-stride INTER, phase 2 K-stride HID.
__global__ __launch_bounds__(512, 2) void gemm_down_moe(
    const u16* __restrict__ Hh,  // [NTOK][INTER]
    const u16* __restrict__ XS,  // [NTOK][HID]
    const u16* __restrict__ Dt,  // down^T   [HID][INTER]
    const u16* __restrict__ Et,  // expert^T [HID][HID]
    float* __restrict__ Y)       // [NTOK][HID]
{
    __shared__ u16 As[2][TEL];
    __shared__ u16 Bs[2][TEL];

    int tid = threadIdx.x;
    int w = tid >> 6, lane = tid & 63;
    int wm = w >> 2, wn = w & 3;
    int quad = lane >> 4, l16 = lane & 15;
    int wm8 = wm * 8, wn4 = wn * 4;

    // XCD chunk swizzle: nwg = 8*64 = 512, 512 % 8 == 0.
    int lid = blockIdx.y * 8 + blockIdx.x;
    int swz = (lid & 7) * (512 / 8) + (lid >> 3);
    int bx = swz & 7, by = swz >> 3;
    int m0 = by * GM, n0 = bx * GN;

    int qp = (lane & 3) ^ (2 * ((lane >> 5) & 1));
    int offI[2], offH2[2];
    offI[0]  = (2 * w * 16 + (lane >> 2)) * INTER + qp * 8;
    offI[1]  = offI[0] + 16 * INTER;
    offH2[0] = (2 * w * 16 + (lane >> 2)) * HID + qp * 8;
    offH2[1] = offH2[0] + 16 * HID;
    const u16* A1 = Hh + (size_t)m0 * INTER;
    const u16* B1 = Dt + (size_t)n0 * INTER;
    const u16* A2 = XS + (size_t)m0 * HID;
    const u16* B2 = Et + (size_t)n0 * HID;

    int so = l16 * 32 + ((quad ^ (2 * ((l16 >> 3) & 1))) * 8);

    floatx4 acc[8][4];
#pragma unroll
    for (int i = 0; i < 8; ++i)
#pragma unroll
        for (int j = 0; j < 4; ++j) acc[i][j] = (floatx4){0.f, 0.f, 0.f, 0.f};

    const int KT1 = INTER / BKt;          // 128
    const int NT  = KT1 + HID / BKt;      // 160

#define ISSA(it_, s_, cg_)                                                    \
    { if ((it_) < KT1)                                                        \
          load_lds16(A1 + (size_t)(offI[s_] + (cg_) * 32 + (it_) * BKt),      \
                     &As[(it_) & 1][((2 * w + (s_)) * 2 + (cg_)) * 512]);     \
      else                                                                    \
          load_lds16(A2 + (size_t)(offH2[s_] + (cg_) * 32 + ((it_) - KT1) * BKt), \
                     &As[(it_) & 1][((2 * w + (s_)) * 2 + (cg_)) * 512]); }
#define ISSB(it_, s_, cg_)                                                    \
    { if ((it_) < KT1)                                                        \
          load_lds16(B1 + (size_t)(offI[s_] + (cg_) * 32 + (it_) * BKt),      \
                     &Bs[(it_) & 1][((2 * w + (s_)) * 2 + (cg_)) * 512]);     \
      else                                                                    \
          load_lds16(B2 + (size_t)(offH2[s_] + (cg_) * 32 + ((it_) - KT1) * BKt), \
                     &Bs[(it_) & 1][((2 * w + (s_)) * 2 + (cg_)) * 512]); }

    bf16x8 afq[4], bfq[4];

    ISSA(0, 0, 0); ISSA(0, 1, 0); ISSB(0, 0, 0); ISSB(0, 1, 0);
    ISSA(0, 0, 1); ISSA(0, 1, 1); ISSB(0, 0, 1); ISSB(0, 1, 1);
    VM_WAIT(4);
    BAR_F();

    for (int t = 0; t < NT - 1; ++t) {
        GTILE(t,
              { ISSA(t + 1, 0, 0); ISSA(t + 1, 1, 0); },
              { ISSB(t + 1, 0, 0); ISSB(t + 1, 1, 0); },
              { ISSA(t + 1, 0, 1); ISSA(t + 1, 1, 1); },
              { ISSB(t + 1, 0, 1); ISSB(t + 1, 1, 1); },
              VM_WAIT(4);, VM_WAIT(4);)
    }
    GTILE(NT - 1, ;, ;, ;, ;, VM_WAIT(0);, ;)
#undef ISSA
#undef ISSB

    int mrow = m0 + wm * 128;
    int ncol = n0 + wn * 64;
#pragma unroll
    for (int i = 0; i < 8; ++i) {
#pragma unroll
        for (int j = 0; j < 4; ++j) {
            int mbase = mrow + i * 16 + quad * 4;
            int n = ncol + j * 16 + l16;
#pragma unroll
            for (int r = 0; r < 4; ++r)
                Y[(size_t)(mbase + r) * HID + n] = acc[i][j][r];
        }
    }
}

// ---------------------------------------------------------------------------
// Kernel 5: LayerNorm in-place over d_out rows
// ---------------------------------------------------------------------------
__global__ __launch_bounds__(256) void ln_kernel(
    float* __restrict__ y, const float* __restrict__ gamma,
    const float* __restrict__ beta)
{
    int token = blockIdx.x;
    int t = threadIdx.x;
    float* yr = y + (size_t)token * HID;
    float4 v0 = ((const float4*)yr)[t];
    float4 v1 = ((const float4*)yr)[t + 256];
    float s  = v0.x + v0.y + v0.z + v0.w + v1.x + v1.y + v1.z + v1.w;
    float ss = v0.x*v0.x + v0.y*v0.y + v0.z*v0.z + v0.w*v0.w
             + v1.x*v1.x + v1.y*v1.y + v1.z*v1.z + v1.w*v1.w;
#pragma unroll
    for (int off = 32; off >= 1; off >>= 1) {
        s  += __shfl_xor(s,  off, 64);
        ss += __shfl_xor(ss, off, 64);
    }
    __shared__ float rs_[4], rss_[4];
    int w = t >> 6, lane = t & 63;
    if (lane == 0) { rs_[w] = s; rss_[w] = ss; }
    __syncthreads();
    s  = rs_[0] + rs_[1] + rs_[2] + rs_[3];
    ss = rss_[0] + rss_[1] + rss_[2] + rss_[3];
    float mu  = s * (1.f / HID);
    float var = ss * (1.f / HID) - mu * mu;
    float rstd = rsqrtf(var + 1e-5f);
    float4 g0 = ((const float4*)gamma)[t];
    float4 g1 = ((const float4*)gamma)[t + 256];
    float4 b0 = ((const float4*)beta)[t];
    float4 b1 = ((const float4*)beta)[t + 256];
    float4 o0, o1;
    o0.x = (v0.x - mu) * rstd * g0.x + b0.x;
    o0.y = (v0.y - mu) * rstd * g0.y + b0.y;
    o0.z = (v0.z - mu) * rstd * g0.z + b0.z;
    o0.w = (v0.w - mu) * rstd * g0.w + b0.w;
    o1.x = (v1.x - mu) * rstd * g1.x + b1.x;
    o1.y = (v1.y - mu) * rstd * g1.y + b1.y;
    o1.z = (v1.z - mu) * rstd * g1.z + b1.z;
    o1.w = (v1.w - mu) * rstd * g1.w + b1.w;
    ((float4*)yr)[t]       = o0;
    ((float4*)yr)[t + 256] = o1;
}

// ---------------------------------------------------------------------------
extern "C" void kernel_launch(void* const* d_in, const int* in_sizes, int n_in,
                              void* d_out, int out_size, void* d_ws, size_t ws_size,
                              hipStream_t stream) {
    const float* x     = (const float*)d_in[0];
    const float* gate  = (const float*)d_in[1];
    const float* up    = (const float*)d_in[2];
    const float* down  = (const float*)d_in[3];
    const float* expw  = (const float*)d_in[4];
    const float* gamma = (const float*)d_in[5];
    const float* beta  = (const float*)d_in[6];
    float* out = (float*)d_out;

    // workspace layout (elements of u16)
    u16* ws  = (u16*)d_ws;
    u16* xb  = ws;                          // 33,554,432  x_bf16
    u16* xsb = xb  + (size_t)NTOK * HID;    // 33,554,432  x*scale bf16
    u16* upT = xsb + (size_t)NTOK * HID;    // 16,777,216  up^T
    u16* dT  = upT + (size_t)INTER * HID;   // 16,777,216  down^T
    u16* eT  = dT  + (size_t)INTER * HID;   //  4,194,304  expert^T
    u16* h   = eT  + (size_t)HID * HID;     // 134,217,728 relu(up(x))^2

    prep_tokens<<<dim3(NTOK / 4), dim3(256), 0, stream>>>(x, gate, xb, xsb);
    transpose_cast<<<dim3(INTER / 32, HID / 32), dim3(256), 0, stream>>>(up, upT, HID, INTER);
    transpose_cast<<<dim3(HID / 32, INTER / 32), dim3(256), 0, stream>>>(down, dT, INTER, HID);
    transpose_cast<<<dim3(HID / 32, HID / 32), dim3(256), 0, stream>>>(expw, eT, HID, HID);
    gemm_up<<<dim3(INTER / GN, NTOK / GM), dim3(512), 0, stream>>>(xb, upT, h);
    gemm_down_moe<<<dim3(HID / GN, NTOK / GM), dim3(512), 0, stream>>>(h, xsb, dT, eT, out);
    ln_kernel<<<dim3(NTOK), dim3(256), 0, stream>>>(out, gamma, beta);
}